// Round 10
// baseline (444.650 us; speedup 1.0000x reference)
//
#include <hip/hip_runtime.h>
#include <math.h>

#define FXSCALE 4398046511104.0   // 2^42
#define WINDOW 7936               // nodes per col-bin (LDS u64[WINDOW] = 63.5 KB)
#define NBMAX 32
#define BINB 2048
#define SCAN_CHUNK 2048

typedef float vfloat4 __attribute__((ext_vector_type(4)));

// fused: blocks [0,nhb) compute h = x@W (fp64, half-wave per row);
// blocks [nhb, nhb+512) build the col-window histogram.
__global__ void k_h_hist(const float* __restrict__ x, const float* __restrict__ W,
                         double* __restrict__ h,
                         const int* __restrict__ ecol, int* __restrict__ binCnt,
                         int N, int C, int E, int NB, int nhb) {
    int b = blockIdx.x;
    if (b < nhb) {
        int t = b * 256 + threadIdx.x;
        int row = t >> 5;
        int lane = t & 31;
        if (row >= N) return;
        const float4* xr = (const float4*)(x + (size_t)row * C);
        const float4* w4 = (const float4*)W;
        int C4 = C >> 2;
        double acc = 0.0;
        for (int c = lane; c < C4; c += 32) {
            float4 xv = xr[c];
            float4 wv = w4[c];
            acc += (double)xv.x * (double)wv.x + (double)xv.y * (double)wv.y
                 + (double)xv.z * (double)wv.z + (double)xv.w * (double)wv.w;
        }
        #pragma unroll
        for (int o = 16; o > 0; o >>= 1) acc += __shfl_xor(acc, o);
        if (lane == 0) h[row] = acc;
    } else {
        __shared__ int cnt[NBMAX];
        int tid = threadIdx.x;
        if (tid < NBMAX) cnt[tid] = 0;
        __syncthreads();
        int hb = b - nhb;
        for (long e = (long)hb * 256 + tid; e < E; e += 512L * 256)
            atomicAdd(&cnt[ecol[e] / WINDOW], 1);
        __syncthreads();
        if (tid < NB && cnt[tid] > 0) atomicAdd(&binCnt[tid], cnt[tid]);
    }
}

// partition edges by col-window: block-local LDS counting sort -> coalesced copy-out.
// binOff computed in-block from binCnt (k_off eliminated).
__global__ void k_bin(const int* __restrict__ erow, const int* __restrict__ ecol,
                      const int* __restrict__ binCnt, int* __restrict__ binWr0,
                      int* __restrict__ binnedRow,
                      unsigned short* __restrict__ binnedCol16, int E, int NB) {
    __shared__ int cnt[NBMAX];
    __shared__ int lbase[NBMAX];
    __shared__ int gbase[NBMAX];
    __shared__ int boff[NBMAX];
    __shared__ int lrow[BINB];
    __shared__ unsigned short lcol[BINB];
    __shared__ unsigned char lbin[BINB];
    int tid = threadIdx.x;
    if (tid < NBMAX) cnt[tid] = 0;
    __syncthreads();
    long b0 = (long)blockIdx.x * BINB;
    int n = (int)((E - b0) < (long)BINB ? (E - b0) : (long)BINB);
    int bA[8], rkA[8], rwA[8];
    unsigned short clA[8];
    #pragma unroll
    for (int k = 0; k < 8; k++) bA[k] = -1;
    int base_i = tid * 8;
    if (base_i + 8 <= n) {
        long e = b0 + base_i;
        int4 r0 = *(const int4*)(erow + e), r1 = *(const int4*)(erow + e + 4);
        int4 c0 = *(const int4*)(ecol + e), c1 = *(const int4*)(ecol + e + 4);
        int rr[8] = {r0.x, r0.y, r0.z, r0.w, r1.x, r1.y, r1.z, r1.w};
        int cc[8] = {c0.x, c0.y, c0.z, c0.w, c1.x, c1.y, c1.z, c1.w};
        #pragma unroll
        for (int k = 0; k < 8; k++) {
            int c = cc[k];
            int bb = c / WINDOW;
            bA[k] = bb; rwA[k] = rr[k]; clA[k] = (unsigned short)(c - bb * WINDOW);
            rkA[k] = atomicAdd(&cnt[bb], 1);
        }
    } else {
        for (int k = 0; k < 8; k++) {
            int i = base_i + k;
            if (i < n) {
                long e = b0 + i;
                int c = ecol[e];
                int bb = c / WINDOW;
                bA[k] = bb; rwA[k] = erow[e]; clA[k] = (unsigned short)(c - bb * WINDOW);
                rkA[k] = atomicAdd(&cnt[bb], 1);
            }
        }
    }
    __syncthreads();
    if (tid == 0) {
        int acc = 0;
        for (int i = 0; i < NB; i++) { lbase[i] = acc; acc += cnt[i]; }
        int acc2 = 0;
        for (int i = 0; i < NB; i++) { boff[i] = acc2; acc2 += binCnt[i]; }
    }
    __syncthreads();
    if (tid < NB && cnt[tid] > 0)
        gbase[tid] = boff[tid] + atomicAdd(&binWr0[tid], cnt[tid]);
    __syncthreads();
    #pragma unroll
    for (int k = 0; k < 8; k++) {
        if (bA[k] >= 0) {
            int l = lbase[bA[k]] + rkA[k];
            lrow[l] = rwA[k];
            lcol[l] = clA[k];
            lbin[l] = (unsigned char)bA[k];
        }
    }
    __syncthreads();
    for (int l = tid; l < n; l += 256) {
        int bb = lbin[l];
        int g = gbase[bb] + (l - lbase[bb]);
        binnedRow[g] = lrow[l];
        binnedCol16[g] = lcol[l];
    }
}

// per-(bin,m) LDS degree histogram -> partial store; LAST block per bin sums
// partials and computes dis = 1/sqrt(deg+1), hd = h*dis (k_dis_hd fused).
__global__ void k_degb(const unsigned short* __restrict__ binnedCol16,
                       const int* __restrict__ binCnt,
                       unsigned int* __restrict__ partialDeg, int* __restrict__ doneD,
                       const double* __restrict__ h,
                       double* __restrict__ dis, double* __restrict__ hd,
                       int N, int Md, int NB) {
    __shared__ unsigned int cnt[WINDOW];
    __shared__ int boff[NBMAX + 1];
    __shared__ int lastFlag;
    int bin = blockIdx.x / Md, m = blockIdx.x % Md;
    int tid = threadIdx.x;
    if (tid == 0) {
        int acc = 0;
        for (int i = 0; i < NB; i++) { boff[i] = acc; acc += binCnt[i]; }
        boff[NB] = acc;
    }
    for (int i = tid; i < WINDOW; i += 256) cnt[i] = 0;
    __syncthreads();
    int st = boff[bin], en = boff[bin + 1];
    for (int idx = st + m * 256 + tid; idx < en; idx += Md * 256)
        atomicAdd(&cnt[binnedCol16[idx]], 1u);
    __syncthreads();
    int wb = bin * WINDOW;
    int wlim = (N - wb) < WINDOW ? (N - wb) : WINDOW;
    for (int i = tid; i < wlim; i += 256)
        partialDeg[(size_t)m * N + wb + i] = cnt[i];
    __threadfence();
    if (tid == 0) lastFlag = (atomicAdd(&doneD[bin], 1) == Md - 1) ? 1 : 0;
    __syncthreads();
    if (!lastFlag) return;
    __threadfence();
    for (int i = tid; i < wlim; i += 256) {
        unsigned int d = 0;
        for (int mm = 0; mm < Md; mm++) d += partialDeg[(size_t)mm * N + wb + i];
        double dd = 1.0 / sqrt((double)d + 1.0);
        dis[wb + i] = dd;
        hd[wb + i] = h[wb + i] * dd;
    }
}

// per-(bin,m) LDS u64 fixed-point accumulate -> partial store; LAST block per
// bin sums partials and computes score32 + tg (k_score fused). Int64 sums are
// order-free => bit-identical to all prior passing rounds.
__global__ void k_aggb(const int* __restrict__ binnedRow,
                       const unsigned short* __restrict__ binnedCol16,
                       const int* __restrict__ binCnt,
                       const double* __restrict__ hd, const double* __restrict__ dis,
                       const double* __restrict__ h, const float* __restrict__ bptr,
                       unsigned long long* __restrict__ partialAgg, int* __restrict__ doneA,
                       float* __restrict__ score32, float* __restrict__ tg,
                       int N, int Ma, int NB) {
    __shared__ unsigned long long acc[WINDOW];   // 63.5 KB
    __shared__ int boff[NBMAX + 1];
    __shared__ int lastFlag;
    int bin = blockIdx.x / Ma, m = blockIdx.x % Ma;
    int tid = threadIdx.x;
    if (tid == 0) {
        int a = 0;
        for (int i = 0; i < NB; i++) { boff[i] = a; a += binCnt[i]; }
        boff[NB] = a;
    }
    for (int i = tid; i < WINDOW; i += 256) acc[i] = 0ULL;
    __syncthreads();
    int st = boff[bin], en = boff[bin + 1];
    int wb = bin * WINDOW;
    for (int idx = st + m * 256 + tid; idx < en; idx += Ma * 256) {
        int r = binnedRow[idx];
        int c16 = binnedCol16[idx];
        long long q = __double2ll_rn(hd[r] * dis[wb + c16] * FXSCALE);
        atomicAdd(&acc[c16], (unsigned long long)q);
    }
    __syncthreads();
    int wlim = (N - wb) < WINDOW ? (N - wb) : WINDOW;
    for (int i = tid; i < wlim; i += 256)
        partialAgg[(size_t)m * N + wb + i] = acc[i];
    __threadfence();
    if (tid == 0) lastFlag = (atomicAdd(&doneA[bin], 1) == Ma - 1) ? 1 : 0;
    __syncthreads();
    if (!lastFlag) return;
    __threadfence();
    double bb = (double)bptr[0];
    for (int i = tid; i < wlim; i += 256) {
        long long a = 0;
        for (int mm = 0; mm < Ma; mm++) a += (long long)partialAgg[(size_t)mm * N + wb + i];
        double agg = (double)a / FXSCALE;
        double d = dis[wb + i];
        double sc = (agg + h[wb + i] * (d * d)) + bb;
        score32[wb + i] = (float)sc;
        tg[wb + i] = (float)tanh(sc);
    }
}

// One THREAD per segment — keep numerics byte-identical to passing rounds.
__global__ void k_seg_np(const float* __restrict__ score32, const int* __restrict__ starts,
                         float* __restrict__ p32, int* __restrict__ keepI,
                         const int* __restrict__ alphaPtr,
                         const int* __restrict__ n1, const int* __restrict__ n2,
                         const int* __restrict__ sent, int N, int S) {
    int g = blockIdx.x * blockDim.x + threadIdx.x;
    if (g >= S) return;
    int st = starts[g];
    int en = (g == S - 1) ? N : starts[g + 1];
    if (en <= st) return;

    int ai = alphaPtr[0];
    float alpha = (ai >= 0 && ai < 1000000) ? (float)ai : __int_as_float(ai);

    float m = -3.402823466e38f;
    for (int i = st; i < en; i++) m = fmaxf(m, score32[i]);

    float Z = 0.0f;
    for (int i = st; i < en; i++) {
        float dm = __fsub_rn(score32[i], m);
        float e = (float)exp((double)dm);   // correctly-rounded fp32 exp
        p32[i] = e;
        Z = __fadd_rn(Z, e);
    }

    float sp = 0.0f, sq = 0.0f, pm = -3.402823466e38f;
    for (int i = st; i < en; i++) {
        float p = __fdiv_rn(p32[i], Z);
        p32[i] = p;
        sp = __fadd_rn(sp, p);
        sq = __fadd_rn(sq, __fmul_rn(p, p));
        pm = fmaxf(pm, p);
    }

    float cnt_ = (float)(en - st);
    float mean = __fdiv_rn(sp, cnt_);
    float var = __fsub_rn(__fdiv_rn(sq, cnt_), __fmul_rn(mean, mean));
    float sd = sqrtf(fmaxf(var, 0.0f));
    float cutoff = __fsub_rn(pm, __fmul_rn(alpha, sd));

    for (int i = st; i < en; i++) keepI[i] = (p32[i] >= cutoff) ? 1 : 0;

    keepI[n1[g]] = 1;
    keepI[n2[g]] = 1;
    keepI[sent[g]] = 1;
}

// single-pass decoupled-lookback scan: keepI -> posF/gate/o_keep.
// status: u64 = (state<<62) | value; state 1=aggregate, 2=inclusive.
__global__ void k_scan(const int* __restrict__ keepI, const float* __restrict__ tg,
                       unsigned long long* __restrict__ stArr,
                       float* __restrict__ posF, float* __restrict__ gate,
                       float* __restrict__ o_keep, int N) {
    int tid = threadIdx.x;
    int b = blockIdx.x;
    long base = (long)b * SCAN_CHUNK + (long)tid * 8;
    int v[8];
    int th = 0;
    #pragma unroll
    for (int k = 0; k < 8; k++) {
        long i = base + k;
        v[k] = (i < N) ? keepI[i] : 0;
        th += v[k];
    }
    __shared__ int sm[256];
    sm[tid] = th; __syncthreads();
    for (int off = 1; off < 256; off <<= 1) {
        int t = (tid >= off) ? sm[tid - off] : 0;
        __syncthreads();
        sm[tid] += t;
        __syncthreads();
    }
    int total = sm[255];
    __shared__ int exclSh;
    if (tid == 0) {
        if (b == 0) {
            atomicExch(&stArr[0], (2ULL << 62) | (unsigned long long)(unsigned)total);
            exclSh = 0;
        } else {
            atomicExch(&stArr[b], (1ULL << 62) | (unsigned long long)(unsigned)total);
            int excl = 0;
            int j = b - 1;
            while (true) {
                unsigned long long s = atomicAdd(&stArr[j], 0ULL);
                unsigned state = (unsigned)(s >> 62);
                if (state == 0) continue;
                excl += (int)(s & 0x3FFFFFFFFFFFFFFFULL);
                if (state == 2u) break;
                j--;
            }
            atomicExch(&stArr[b], (2ULL << 62) | (unsigned long long)(unsigned)(excl + total));
            exclSh = excl;
        }
    }
    __syncthreads();
    int run = exclSh + sm[tid] - th;
    #pragma unroll
    for (int k = 0; k < 8; k++) {
        long i = base + k;
        if (i < N) {
            posF[i] = v[k] ? (float)(run + v[k] - 1) : -1.0f;
            gate[i] = v[k] ? tg[i] : 0.0f;
            o_keep[i] = v[k] ? 1.0f : 0.0f;
            run += v[k];
        }
    }
}

// fused outputs: [0,nxb) x_out float4s; [nxb,nxb+neb4) edges x4; rest nodes
__global__ void k_out(const float4* __restrict__ x4, const float* __restrict__ gate,
                      float* __restrict__ o_x, long total4,
                      const int* __restrict__ erow, const int* __restrict__ ecol,
                      const float* __restrict__ posF,
                      float* __restrict__ o_edge, float* __restrict__ o_ekeep, int E,
                      const int* __restrict__ n1, const int* __restrict__ n2,
                      const int* __restrict__ sent,
                      float* __restrict__ o_n1, float* __restrict__ o_n2,
                      float* __restrict__ o_sent, int S,
                      int nxb, int neb4) {
    int b = blockIdx.x;
    if (b < nxb) {
        long idx = (long)b * blockDim.x + threadIdx.x;
        if (idx >= total4) return;
        int row = (int)(idx >> 5);   // C/4 = 32 float4 per row
        float g = gate[row];
        float4 v = x4[idx];
        vfloat4 r = { v.x * g, v.y * g, v.z * g, v.w * g };
        __builtin_nontemporal_store(r, (vfloat4*)o_x + idx);
    } else if (b < nxb + neb4) {
        long e0 = ((long)(b - nxb) * blockDim.x + threadIdx.x) * 4;
        if (e0 >= E) return;
        if (e0 + 3 < E) {
            int4 r4 = *(const int4*)(erow + e0);
            int4 c4 = *(const int4*)(ecol + e0);
            vfloat4 oer, oec, ok;
            #pragma unroll
            for (int k = 0; k < 4; k++) {
                int r = (&r4.x)[k], c = (&c4.x)[k];
                float pr = posF[r], pc = posF[c];
                bool ek = (pr >= 0.0f) && (pc >= 0.0f);
                oer[k] = ek ? pr : -1.0f;
                oec[k] = ek ? pc : -1.0f;
                ok[k]  = ek ? 1.0f : 0.0f;
            }
            __builtin_nontemporal_store(oer, (vfloat4*)(o_edge + e0));
            __builtin_nontemporal_store(oec, (vfloat4*)(o_edge + (size_t)E + e0));
            __builtin_nontemporal_store(ok,  (vfloat4*)(o_ekeep + e0));
        } else {
            for (long e = e0; e < E; e++) {
                int r = erow[e], c = ecol[e];
                float pr = posF[r], pc = posF[c];
                bool ek = (pr >= 0.0f) && (pc >= 0.0f);
                o_edge[e] = ek ? pr : -1.0f;
                o_edge[(size_t)E + e] = ek ? pc : -1.0f;
                o_ekeep[e] = ek ? 1.0f : 0.0f;
            }
        }
    } else {
        int i = (b - nxb - neb4) * blockDim.x + threadIdx.x;
        if (i >= S) return;
        o_n1[i] = posF[n1[i]];
        o_n2[i] = posF[n2[i]];
        o_sent[i] = posF[sent[i]];
    }
}

extern "C" void kernel_launch(void* const* d_in, const int* in_sizes, int n_in,
                              void* d_out, int out_size, void* d_ws, size_t ws_size,
                              hipStream_t stream) {
    const float* x    = (const float*)d_in[0];
    const int*   eidx = (const int*)d_in[1];
    const int*   n1   = (const int*)d_in[2];
    const int*   n2   = (const int*)d_in[3];
    const int*   sent = (const int*)d_in[4];
    const float* W    = (const float*)d_in[5];
    const float* bp   = (const float*)d_in[6];
    const int*   alphaPtr = (const int*)d_in[7];

    int C = in_sizes[5];                 // W is [C,1]
    int N = in_sizes[0] / C;
    int E = in_sizes[1] / 2;
    int S = in_sizes[2];

    const int* erow = eidx;
    const int* ecol = eidx + E;

    int NB = (N + WINDOW - 1) / WINDOW;  // 26 for N=200000
    const int Md = 8, Ma = 8;

    // workspace layout — zeroed control region first (binCnt..scanSt)
    char* ws = (char*)d_ws;
    size_t off = 0;
    auto alloc = [&](size_t bytes) { void* p = ws + off; off += (bytes + 255) & ~(size_t)255; return p; };
    int*   binCnt = (int*)  alloc(NBMAX * 4);
    int*   binWr0 = (int*)  alloc(NBMAX * 4);
    int*   doneD  = (int*)  alloc(NBMAX * 4);
    int*   doneA  = (int*)  alloc(NBMAX * 4);
    unsigned long long* scanSt = (unsigned long long*)alloc(256 * 8);
    size_t zeroBytes = (size_t)((char*)(scanSt + 256) - (char*)binCnt);
    int*   binnedRow = (int*)alloc((size_t)E * 4);
    unsigned short* binnedCol16 = (unsigned short*)alloc((size_t)E * 2);
    unsigned int* partialDeg = (unsigned int*)alloc((size_t)Md * N * 4);
    unsigned long long* partialAgg = (unsigned long long*)alloc((size_t)Ma * N * 8);
    double* h     = (double*)alloc((size_t)N * 8);
    double* dis   = (double*)alloc((size_t)N * 8);
    double* hd    = (double*)alloc((size_t)N * 8);
    float* score32 = (float*)alloc((size_t)N * 4);
    float* p32    = (float*)alloc((size_t)N * 4);
    float* tg     = (float*)alloc((size_t)N * 4);
    int*   keepI  = (int*)  alloc((size_t)N * 4);
    float* posF   = (float*)alloc((size_t)N * 4);
    float* gate   = (float*)alloc((size_t)N * 4);

    // output layout (all float32, concatenated)
    float* o_x     = (float*)d_out;
    float* o_edge  = o_x + (size_t)N * C;
    float* o_keep  = o_edge + 2 * (size_t)E;
    float* o_ekeep = o_keep + N;
    float* o_n1    = o_ekeep + E;
    float* o_n2    = o_n1 + S;
    float* o_sent  = o_n2 + S;

    (void)hipMemsetAsync(binCnt, 0, zeroBytes, stream);

    int nhb = (N * 32 + 255) / 256;
    k_h_hist<<<nhb + 512, 256, 0, stream>>>(x, W, h, ecol, binCnt, N, C, E, NB, nhb);
    int nBatches = (int)(((long)E + BINB - 1) / BINB);
    k_bin<<<nBatches, 256, 0, stream>>>(erow, ecol, binCnt, binWr0, binnedRow, binnedCol16, E, NB);
    k_degb<<<NB * Md, 256, 0, stream>>>(binnedCol16, binCnt, partialDeg, doneD, h, dis, hd, N, Md, NB);
    k_aggb<<<NB * Ma, 256, 0, stream>>>(binnedRow, binnedCol16, binCnt, hd, dis, h, bp,
                                        partialAgg, doneA, score32, tg, N, Ma, NB);
    k_seg_np<<<(S + 255) / 256, 256, 0, stream>>>(score32, n1, p32, keepI, alphaPtr, n1, n2, sent, N, S);
    int nb = (N + SCAN_CHUNK - 1) / SCAN_CHUNK;
    k_scan<<<nb, 256, 0, stream>>>(keepI, tg, scanSt, posF, gate, o_keep, N);

    long total4 = (long)N * (C / 4);
    int nxb = (int)((total4 + 255) / 256);
    long e4 = (E + 3) / 4;
    int neb4 = (int)((e4 + 255) / 256);
    int nsb = (S + 255) / 256;
    k_out<<<nxb + neb4 + nsb, 256, 0, stream>>>(
        (const float4*)x, gate, o_x, total4,
        erow, ecol, posF, o_edge, o_ekeep, E,
        n1, n2, sent, o_n1, o_n2, o_sent, S, nxb, neb4);
}

// Round 11
// 252.359 us; speedup vs baseline: 1.7620x; 1.7620x over previous
//
#include <hip/hip_runtime.h>
#include <math.h>

#define FXSCALE 4398046511104.0   // 2^42
#define WINDOW 7936               // nodes per col-bin (LDS u64[WINDOW] = 63.5 KB)
#define NBMAX 32
#define BINB 2048
#define SCAN_CHUNK 2048

typedef float vfloat4 __attribute__((ext_vector_type(4)));

// fused: blocks [0,nhb) compute h = x@W (fp64, half-wave per row);
// blocks [nhb, nhb+512) build the col-window histogram.
__global__ void k_h_hist(const float* __restrict__ x, const float* __restrict__ W,
                         double* __restrict__ h,
                         const int* __restrict__ ecol, int* __restrict__ binCnt,
                         int N, int C, int E, int NB, int nhb) {
    int b = blockIdx.x;
    if (b < nhb) {
        int t = b * 256 + threadIdx.x;
        int row = t >> 5;
        int lane = t & 31;
        if (row >= N) return;
        const float4* xr = (const float4*)(x + (size_t)row * C);
        const float4* w4 = (const float4*)W;
        int C4 = C >> 2;
        double acc = 0.0;
        for (int c = lane; c < C4; c += 32) {
            float4 xv = xr[c];
            float4 wv = w4[c];
            acc += (double)xv.x * (double)wv.x + (double)xv.y * (double)wv.y
                 + (double)xv.z * (double)wv.z + (double)xv.w * (double)wv.w;
        }
        #pragma unroll
        for (int o = 16; o > 0; o >>= 1) acc += __shfl_xor(acc, o);
        if (lane == 0) h[row] = acc;
    } else {
        __shared__ int cnt[NBMAX];
        int tid = threadIdx.x;
        if (tid < NBMAX) cnt[tid] = 0;
        __syncthreads();
        int hb = b - nhb;
        for (long e = (long)hb * 256 + tid; e < E; e += 512L * 256)
            atomicAdd(&cnt[ecol[e] / WINDOW], 1);
        __syncthreads();
        if (tid < NB && cnt[tid] > 0) atomicAdd(&binCnt[tid], cnt[tid]);
    }
}

// exclusive scan of bins + init write cursors (1 thread)
__global__ void k_off(const int* __restrict__ binCnt, int* __restrict__ binOff,
                      int* __restrict__ binWr, int NB) {
    if (threadIdx.x != 0 || blockIdx.x != 0) return;
    int acc = 0;
    for (int i = 0; i < NB; i++) {
        binOff[i] = acc;
        binWr[i] = acc;
        acc += binCnt[i];
    }
    binOff[NB] = acc;
}

// partition edges by col-window: block-local LDS counting sort -> coalesced copy-out.
__global__ void k_bin(const int* __restrict__ erow, const int* __restrict__ ecol,
                      int* __restrict__ binWr, int* __restrict__ binnedRow,
                      unsigned short* __restrict__ binnedCol16, int E, int NB) {
    __shared__ int cnt[NBMAX];
    __shared__ int lbase[NBMAX];
    __shared__ int gbase[NBMAX];
    __shared__ int lrow[BINB];
    __shared__ unsigned short lcol[BINB];
    __shared__ unsigned char lbin[BINB];
    int tid = threadIdx.x;
    if (tid < NBMAX) cnt[tid] = 0;
    __syncthreads();
    long b0 = (long)blockIdx.x * BINB;
    int n = (int)((E - b0) < (long)BINB ? (E - b0) : (long)BINB);
    int bA[8], rkA[8], rwA[8];
    unsigned short clA[8];
    #pragma unroll
    for (int k = 0; k < 8; k++) bA[k] = -1;
    int base_i = tid * 8;
    if (base_i + 8 <= n) {
        long e = b0 + base_i;
        int4 r0 = *(const int4*)(erow + e), r1 = *(const int4*)(erow + e + 4);
        int4 c0 = *(const int4*)(ecol + e), c1 = *(const int4*)(ecol + e + 4);
        int rr[8] = {r0.x, r0.y, r0.z, r0.w, r1.x, r1.y, r1.z, r1.w};
        int cc[8] = {c0.x, c0.y, c0.z, c0.w, c1.x, c1.y, c1.z, c1.w};
        #pragma unroll
        for (int k = 0; k < 8; k++) {
            int c = cc[k];
            int bb = c / WINDOW;
            bA[k] = bb; rwA[k] = rr[k]; clA[k] = (unsigned short)(c - bb * WINDOW);
            rkA[k] = atomicAdd(&cnt[bb], 1);
        }
    } else {
        for (int k = 0; k < 8; k++) {
            int i = base_i + k;
            if (i < n) {
                long e = b0 + i;
                int c = ecol[e];
                int bb = c / WINDOW;
                bA[k] = bb; rwA[k] = erow[e]; clA[k] = (unsigned short)(c - bb * WINDOW);
                rkA[k] = atomicAdd(&cnt[bb], 1);
            }
        }
    }
    __syncthreads();
    if (tid == 0) {
        int acc = 0;
        for (int i = 0; i < NB; i++) { lbase[i] = acc; acc += cnt[i]; }
    }
    __syncthreads();
    if (tid < NB && cnt[tid] > 0) gbase[tid] = atomicAdd(&binWr[tid], cnt[tid]);
    __syncthreads();
    #pragma unroll
    for (int k = 0; k < 8; k++) {
        if (bA[k] >= 0) {
            int l = lbase[bA[k]] + rkA[k];
            lrow[l] = rwA[k];
            lcol[l] = clA[k];
            lbin[l] = (unsigned char)bA[k];
        }
    }
    __syncthreads();
    for (int l = tid; l < n; l += 256) {
        int bb = lbin[l];
        int g = gbase[bb] + (l - lbase[bb]);
        binnedRow[g] = lrow[l];
        binnedCol16[g] = lcol[l];
    }
}

// per-(bin,m) LDS degree histogram -> coalesced partial store (no global atomics)
__global__ void k_degb(const unsigned short* __restrict__ binnedCol16,
                       const int* __restrict__ binOff,
                       unsigned int* __restrict__ partialDeg, int N, int Md) {
    __shared__ unsigned int cnt[WINDOW];
    int bin = blockIdx.x / Md, m = blockIdx.x % Md;
    int tid = threadIdx.x;
    for (int i = tid; i < WINDOW; i += blockDim.x) cnt[i] = 0;
    __syncthreads();
    int st = binOff[bin], en = binOff[bin + 1];
    for (int idx = st + m * (int)blockDim.x + tid; idx < en; idx += Md * (int)blockDim.x)
        atomicAdd(&cnt[binnedCol16[idx]], 1u);
    __syncthreads();
    int wb = bin * WINDOW;
    for (int i = tid; i < WINDOW && wb + i < N; i += blockDim.x)
        partialDeg[(size_t)m * N + wb + i] = cnt[i];
}

// dis = 1/sqrt(deg+1); hd = h*dis
__global__ void k_dis_hd(const unsigned int* __restrict__ partialDeg,
                         const double* __restrict__ h,
                         double* __restrict__ dis, double* __restrict__ hd,
                         int N, int Md) {
    int i = blockIdx.x * blockDim.x + threadIdx.x;
    if (i >= N) return;
    unsigned int dsum = 0;
    for (int m = 0; m < Md; m++) dsum += partialDeg[(size_t)m * N + i];
    double d = 1.0 / sqrt((double)dsum + 1.0);
    dis[i] = d;
    hd[i] = h[i] * d;
}

// per-(bin,m) LDS u64 fixed-point accumulate -> coalesced partial store.
__global__ void k_aggb(const int* __restrict__ binnedRow,
                       const unsigned short* __restrict__ binnedCol16,
                       const int* __restrict__ binOff,
                       const double* __restrict__ hd, const double* __restrict__ dis,
                       unsigned long long* __restrict__ partialAgg, int N, int Ma) {
    __shared__ unsigned long long acc[WINDOW];   // 63.5 KB
    int bin = blockIdx.x / Ma, m = blockIdx.x % Ma;
    int tid = threadIdx.x;
    for (int i = tid; i < WINDOW; i += blockDim.x) acc[i] = 0ULL;
    __syncthreads();
    int st = binOff[bin], en = binOff[bin + 1];
    int wb = bin * WINDOW;
    for (int idx = st + m * (int)blockDim.x + tid; idx < en; idx += Ma * (int)blockDim.x) {
        int r = binnedRow[idx];
        int c16 = binnedCol16[idx];
        long long q = __double2ll_rn(hd[r] * dis[wb + c16] * FXSCALE);
        atomicAdd(&acc[c16], (unsigned long long)q);
    }
    __syncthreads();
    for (int i = tid; i < WINDOW && wb + i < N; i += blockDim.x)
        partialAgg[(size_t)m * N + wb + i] = acc[i];
}

// score (fp64, rounded to fp32) ; tg = tanh(score) fp32
__global__ void k_score(const unsigned long long* __restrict__ partialAgg,
                        const double* __restrict__ h, const double* __restrict__ dis,
                        const float* __restrict__ bptr,
                        float* __restrict__ score32, float* __restrict__ tg,
                        int N, int Ma) {
    int i = blockIdx.x * blockDim.x + threadIdx.x;
    if (i >= N) return;
    long long acc = 0;
    for (int m = 0; m < Ma; m++) acc += (long long)partialAgg[(size_t)m * N + i];
    double agg = (double)acc / FXSCALE;
    double d = dis[i];
    double sc = (agg + h[i] * (d * d)) + (double)bptr[0];
    score32[i] = (float)sc;
    tg[i] = (float)tanh(sc);
}

// One THREAD per segment — keep numerics byte-identical to passing rounds.
__global__ void k_seg_np(const float* __restrict__ score32, const int* __restrict__ starts,
                         float* __restrict__ p32, int* __restrict__ keepI,
                         const int* __restrict__ alphaPtr,
                         const int* __restrict__ n1, const int* __restrict__ n2,
                         const int* __restrict__ sent, int N, int S) {
    int g = blockIdx.x * blockDim.x + threadIdx.x;
    if (g >= S) return;
    int st = starts[g];
    int en = (g == S - 1) ? N : starts[g + 1];
    if (en <= st) return;

    int ai = alphaPtr[0];
    float alpha = (ai >= 0 && ai < 1000000) ? (float)ai : __int_as_float(ai);

    float m = -3.402823466e38f;
    for (int i = st; i < en; i++) m = fmaxf(m, score32[i]);

    float Z = 0.0f;
    for (int i = st; i < en; i++) {
        float dm = __fsub_rn(score32[i], m);
        float e = (float)exp((double)dm);   // correctly-rounded fp32 exp
        p32[i] = e;
        Z = __fadd_rn(Z, e);
    }

    float sp = 0.0f, sq = 0.0f, pm = -3.402823466e38f;
    for (int i = st; i < en; i++) {
        float p = __fdiv_rn(p32[i], Z);
        p32[i] = p;
        sp = __fadd_rn(sp, p);
        sq = __fadd_rn(sq, __fmul_rn(p, p));
        pm = fmaxf(pm, p);
    }

    float cnt_ = (float)(en - st);
    float mean = __fdiv_rn(sp, cnt_);
    float var = __fsub_rn(__fdiv_rn(sq, cnt_), __fmul_rn(mean, mean));
    float sd = sqrtf(fmaxf(var, 0.0f));
    float cutoff = __fsub_rn(pm, __fmul_rn(alpha, sd));

    for (int i = st; i < en; i++) keepI[i] = (p32[i] >= cutoff) ? 1 : 0;

    keepI[n1[g]] = 1;
    keepI[n2[g]] = 1;
    keepI[sent[g]] = 1;
}

// single-pass decoupled-lookback scan: keepI -> posF/gate/o_keep.
// status: u64 = (state<<62) | value; state 1=aggregate, 2=inclusive.
// Atomics only (no threadfence) — device-scope atomicAdd/Exch bypass L2 coherency issues.
__global__ void k_scan(const int* __restrict__ keepI, const float* __restrict__ tg,
                       unsigned long long* __restrict__ stArr,
                       float* __restrict__ posF, float* __restrict__ gate,
                       float* __restrict__ o_keep, int N) {
    int tid = threadIdx.x;
    int b = blockIdx.x;
    long base = (long)b * SCAN_CHUNK + (long)tid * 8;
    int v[8];
    int th = 0;
    #pragma unroll
    for (int k = 0; k < 8; k++) {
        long i = base + k;
        v[k] = (i < N) ? keepI[i] : 0;
        th += v[k];
    }
    __shared__ int sm[256];
    sm[tid] = th; __syncthreads();
    for (int off = 1; off < 256; off <<= 1) {
        int t = (tid >= off) ? sm[tid - off] : 0;
        __syncthreads();
        sm[tid] += t;
        __syncthreads();
    }
    int total = sm[255];
    __shared__ int exclSh;
    if (tid == 0) {
        if (b == 0) {
            atomicExch(&stArr[0], (2ULL << 62) | (unsigned long long)(unsigned)total);
            exclSh = 0;
        } else {
            atomicExch(&stArr[b], (1ULL << 62) | (unsigned long long)(unsigned)total);
            int excl = 0;
            int j = b - 1;
            while (true) {
                unsigned long long s = atomicAdd(&stArr[j], 0ULL);
                unsigned state = (unsigned)(s >> 62);
                if (state == 0) continue;
                excl += (int)(s & 0x3FFFFFFFFFFFFFFFULL);
                if (state == 2u) break;
                j--;
            }
            atomicExch(&stArr[b], (2ULL << 62) | (unsigned long long)(unsigned)(excl + total));
            exclSh = excl;
        }
    }
    __syncthreads();
    int run = exclSh + sm[tid] - th;
    #pragma unroll
    for (int k = 0; k < 8; k++) {
        long i = base + k;
        if (i < N) {
            posF[i] = v[k] ? (float)(run + v[k] - 1) : -1.0f;
            gate[i] = v[k] ? tg[i] : 0.0f;
            o_keep[i] = v[k] ? 1.0f : 0.0f;
            run += v[k];
        }
    }
}

// fused outputs: [0,nxb) x_out float4s; [nxb,nxb+neb4) edges x4; rest nodes
__global__ void k_out(const float4* __restrict__ x4, const float* __restrict__ gate,
                      float* __restrict__ o_x, long total4,
                      const int* __restrict__ erow, const int* __restrict__ ecol,
                      const float* __restrict__ posF,
                      float* __restrict__ o_edge, float* __restrict__ o_ekeep, int E,
                      const int* __restrict__ n1, const int* __restrict__ n2,
                      const int* __restrict__ sent,
                      float* __restrict__ o_n1, float* __restrict__ o_n2,
                      float* __restrict__ o_sent, int S,
                      int nxb, int neb4) {
    int b = blockIdx.x;
    if (b < nxb) {
        long idx = (long)b * blockDim.x + threadIdx.x;
        if (idx >= total4) return;
        int row = (int)(idx >> 5);   // C/4 = 32 float4 per row
        float g = gate[row];
        float4 v = x4[idx];
        vfloat4 r = { v.x * g, v.y * g, v.z * g, v.w * g };
        __builtin_nontemporal_store(r, (vfloat4*)o_x + idx);
    } else if (b < nxb + neb4) {
        long e0 = ((long)(b - nxb) * blockDim.x + threadIdx.x) * 4;
        if (e0 >= E) return;
        if (e0 + 3 < E) {
            int4 r4 = *(const int4*)(erow + e0);
            int4 c4 = *(const int4*)(ecol + e0);
            vfloat4 oer, oec, ok;
            #pragma unroll
            for (int k = 0; k < 4; k++) {
                int r = (&r4.x)[k], c = (&c4.x)[k];
                float pr = posF[r], pc = posF[c];
                bool ek = (pr >= 0.0f) && (pc >= 0.0f);
                oer[k] = ek ? pr : -1.0f;
                oec[k] = ek ? pc : -1.0f;
                ok[k]  = ek ? 1.0f : 0.0f;
            }
            __builtin_nontemporal_store(oer, (vfloat4*)(o_edge + e0));
            __builtin_nontemporal_store(oec, (vfloat4*)(o_edge + (size_t)E + e0));
            __builtin_nontemporal_store(ok,  (vfloat4*)(o_ekeep + e0));
        } else {
            for (long e = e0; e < E; e++) {
                int r = erow[e], c = ecol[e];
                float pr = posF[r], pc = posF[c];
                bool ek = (pr >= 0.0f) && (pc >= 0.0f);
                o_edge[e] = ek ? pr : -1.0f;
                o_edge[(size_t)E + e] = ek ? pc : -1.0f;
                o_ekeep[e] = ek ? 1.0f : 0.0f;
            }
        }
    } else {
        int i = (b - nxb - neb4) * blockDim.x + threadIdx.x;
        if (i >= S) return;
        o_n1[i] = posF[n1[i]];
        o_n2[i] = posF[n2[i]];
        o_sent[i] = posF[sent[i]];
    }
}

extern "C" void kernel_launch(void* const* d_in, const int* in_sizes, int n_in,
                              void* d_out, int out_size, void* d_ws, size_t ws_size,
                              hipStream_t stream) {
    const float* x    = (const float*)d_in[0];
    const int*   eidx = (const int*)d_in[1];
    const int*   n1   = (const int*)d_in[2];
    const int*   n2   = (const int*)d_in[3];
    const int*   sent = (const int*)d_in[4];
    const float* W    = (const float*)d_in[5];
    const float* bp   = (const float*)d_in[6];
    const int*   alphaPtr = (const int*)d_in[7];

    int C = in_sizes[5];                 // W is [C,1]
    int N = in_sizes[0] / C;
    int E = in_sizes[1] / 2;
    int S = in_sizes[2];

    const int* erow = eidx;
    const int* ecol = eidx + E;

    int NB = (N + WINDOW - 1) / WINDOW;  // 26 for N=200000
    const int Md = 8, Ma = 8;

    // workspace layout — zeroed control region first (binCnt + scanSt)
    char* ws = (char*)d_ws;
    size_t off = 0;
    auto alloc = [&](size_t bytes) { void* p = ws + off; off += (bytes + 255) & ~(size_t)255; return p; };
    int*   binCnt = (int*)  alloc(NBMAX * 4);
    unsigned long long* scanSt = (unsigned long long*)alloc(256 * 8);
    size_t zeroBytes = (size_t)((char*)(scanSt + 256) - (char*)binCnt);
    int*   binOff = (int*)  alloc((NBMAX + 1) * 4);
    int*   binWr  = (int*)  alloc(NBMAX * 4);
    int*   binnedRow = (int*)alloc((size_t)E * 4);
    unsigned short* binnedCol16 = (unsigned short*)alloc((size_t)E * 2);
    unsigned int* partialDeg = (unsigned int*)alloc((size_t)Md * N * 4);
    unsigned long long* partialAgg = (unsigned long long*)alloc((size_t)Ma * N * 8);
    double* h     = (double*)alloc((size_t)N * 8);
    double* dis   = (double*)alloc((size_t)N * 8);
    double* hd    = (double*)alloc((size_t)N * 8);
    float* score32 = (float*)alloc((size_t)N * 4);
    float* p32    = (float*)alloc((size_t)N * 4);
    float* tg     = (float*)alloc((size_t)N * 4);
    int*   keepI  = (int*)  alloc((size_t)N * 4);
    float* posF   = (float*)alloc((size_t)N * 4);
    float* gate   = (float*)alloc((size_t)N * 4);

    // output layout (all float32, concatenated)
    float* o_x     = (float*)d_out;
    float* o_edge  = o_x + (size_t)N * C;
    float* o_keep  = o_edge + 2 * (size_t)E;
    float* o_ekeep = o_keep + N;
    float* o_n1    = o_ekeep + E;
    float* o_n2    = o_n1 + S;
    float* o_sent  = o_n2 + S;

    (void)hipMemsetAsync(binCnt, 0, zeroBytes, stream);

    int nhb = (N * 32 + 255) / 256;
    k_h_hist<<<nhb + 512, 256, 0, stream>>>(x, W, h, ecol, binCnt, N, C, E, NB, nhb);
    k_off<<<1, 64, 0, stream>>>(binCnt, binOff, binWr, NB);
    int nBatches = (int)(((long)E + BINB - 1) / BINB);
    k_bin<<<nBatches, 256, 0, stream>>>(erow, ecol, binWr, binnedRow, binnedCol16, E, NB);
    k_degb<<<NB * Md, 256, 0, stream>>>(binnedCol16, binOff, partialDeg, N, Md);
    k_dis_hd<<<(N + 255) / 256, 256, 0, stream>>>(partialDeg, h, dis, hd, N, Md);
    k_aggb<<<NB * Ma, 256, 0, stream>>>(binnedRow, binnedCol16, binOff, hd, dis, partialAgg, N, Ma);
    k_score<<<(N + 255) / 256, 256, 0, stream>>>(partialAgg, h, dis, bp, score32, tg, N, Ma);
    k_seg_np<<<(S + 255) / 256, 256, 0, stream>>>(score32, n1, p32, keepI, alphaPtr, n1, n2, sent, N, S);
    int nb = (N + SCAN_CHUNK - 1) / SCAN_CHUNK;
    k_scan<<<nb, 256, 0, stream>>>(keepI, tg, scanSt, posF, gate, o_keep, N);

    long total4 = (long)N * (C / 4);
    int nxb = (int)((total4 + 255) / 256);
    long e4 = (E + 3) / 4;
    int neb4 = (int)((e4 + 255) / 256);
    int nsb = (S + 255) / 256;
    k_out<<<nxb + neb4 + nsb, 256, 0, stream>>>(
        (const float4*)x, gate, o_x, total4,
        erow, ecol, posF, o_edge, o_ekeep, E,
        n1, n2, sent, o_n1, o_n2, o_sent, S, nxb, neb4);
}

// Round 12
// 251.726 us; speedup vs baseline: 1.7664x; 1.0025x over previous
//
#include <hip/hip_runtime.h>
#include <math.h>

#define FXSCALE 4398046511104.0   // 2^42
#define WINDOW 1984               // nodes per col-bin (LDS u64[WINDOW] = 15.9 KB)
#define NBMAX 128
#define BINB 2048
#define SCAN_CHUNK 2048

typedef float vfloat4 __attribute__((ext_vector_type(4)));

// col-window histogram (512 blocks, LDS counters)
__global__ void k_hist(const int* __restrict__ ecol, int* __restrict__ binCnt,
                       int E, int NB) {
    __shared__ int cnt[NBMAX];
    int tid = threadIdx.x;
    for (int i = tid; i < NBMAX; i += 256) cnt[i] = 0;
    __syncthreads();
    for (long e = (long)blockIdx.x * 256 + tid; e < E; e += 512L * 256)
        atomicAdd(&cnt[ecol[e] / WINDOW], 1);
    __syncthreads();
    for (int i = tid; i < NB; i += 256)
        if (cnt[i] > 0) atomicAdd(&binCnt[i], cnt[i]);
}

// fused: blocks [0,nBatches) partition edges (LDS counting sort, coalesced copy-out);
// blocks [nBatches, nBatches+nhb) compute h = x@W (fp64, half-wave per row).
__global__ void k_bin_h(const int* __restrict__ erow, const int* __restrict__ ecol,
                        const int* __restrict__ binCnt, int* __restrict__ binWr0,
                        int* __restrict__ binnedRow,
                        unsigned short* __restrict__ binnedCol16,
                        const float* __restrict__ x, const float* __restrict__ W,
                        double* __restrict__ h,
                        int E, int NB, int N, int C, int nBatches) {
    int blk = blockIdx.x;
    if (blk >= nBatches) {
        int t = (blk - nBatches) * 256 + threadIdx.x;
        int row = t >> 5;
        int lane = t & 31;
        if (row >= N) return;
        const float4* xr = (const float4*)(x + (size_t)row * C);
        const float4* w4 = (const float4*)W;
        int C4 = C >> 2;
        double acc = 0.0;
        for (int c = lane; c < C4; c += 32) {
            float4 xv = xr[c];
            float4 wv = w4[c];
            acc += (double)xv.x * (double)wv.x + (double)xv.y * (double)wv.y
                 + (double)xv.z * (double)wv.z + (double)xv.w * (double)wv.w;
        }
        #pragma unroll
        for (int o = 16; o > 0; o >>= 1) acc += __shfl_xor(acc, o);
        if (lane == 0) h[row] = acc;
        return;
    }
    __shared__ int cnt[NBMAX];
    __shared__ int lbase[NBMAX];
    __shared__ int gbase[NBMAX];
    __shared__ int lrow[BINB];
    __shared__ unsigned short lcol[BINB];
    __shared__ unsigned char lbin[BINB];
    int tid = threadIdx.x;
    for (int i = tid; i < NBMAX; i += 256) cnt[i] = 0;
    __syncthreads();
    long b0 = (long)blk * BINB;
    int n = (int)((E - b0) < (long)BINB ? (E - b0) : (long)BINB);
    int bA[8], rkA[8], rwA[8];
    unsigned short clA[8];
    #pragma unroll
    for (int k = 0; k < 8; k++) bA[k] = -1;
    int base_i = tid * 8;
    if (base_i + 8 <= n) {
        long e = b0 + base_i;
        int4 r0 = *(const int4*)(erow + e), r1 = *(const int4*)(erow + e + 4);
        int4 c0 = *(const int4*)(ecol + e), c1 = *(const int4*)(ecol + e + 4);
        int rr[8] = {r0.x, r0.y, r0.z, r0.w, r1.x, r1.y, r1.z, r1.w};
        int cc[8] = {c0.x, c0.y, c0.z, c0.w, c1.x, c1.y, c1.z, c1.w};
        #pragma unroll
        for (int k = 0; k < 8; k++) {
            int c = cc[k];
            int bb = c / WINDOW;
            bA[k] = bb; rwA[k] = rr[k]; clA[k] = (unsigned short)(c - bb * WINDOW);
            rkA[k] = atomicAdd(&cnt[bb], 1);
        }
    } else {
        for (int k = 0; k < 8; k++) {
            int i = base_i + k;
            if (i < n) {
                long e = b0 + i;
                int c = ecol[e];
                int bb = c / WINDOW;
                bA[k] = bb; rwA[k] = erow[e]; clA[k] = (unsigned short)(c - bb * WINDOW);
                rkA[k] = atomicAdd(&cnt[bb], 1);
            }
        }
    }
    __syncthreads();
    if (tid == 0) {
        int acc = 0;
        #pragma unroll 1
        for (int i = 0; i < NB; i++) { lbase[i] = acc; acc += cnt[i]; }
    }
    __syncthreads();
    // gbase = global bin offset (prefix of binCnt) + cursor within bin
    if (tid < NB && cnt[tid] > 0) {
        int boff = 0;
        for (int i = 0; i < tid; i++) boff += binCnt[i];
        gbase[tid] = boff + atomicAdd(&binWr0[tid], cnt[tid]);
    }
    __syncthreads();
    #pragma unroll
    for (int k = 0; k < 8; k++) {
        if (bA[k] >= 0) {
            int l = lbase[bA[k]] + rkA[k];
            lrow[l] = rwA[k];
            lcol[l] = clA[k];
            lbin[l] = (unsigned char)bA[k];
        }
    }
    __syncthreads();
    for (int l = tid; l < n; l += 256) {
        int bb = lbin[l];
        int g = gbase[bb] + (l - lbase[bb]);
        binnedRow[g] = lrow[l];
        binnedCol16[g] = lcol[l];
    }
}

// per-(bin,m) LDS degree histogram -> coalesced partial store (no global atomics)
__global__ void k_degb(const unsigned short* __restrict__ binnedCol16,
                       const int* __restrict__ binCnt,
                       unsigned int* __restrict__ partialDeg, int N, int Md, int NB) {
    __shared__ unsigned int cnt[WINDOW];
    __shared__ int boff[2];
    int bin = blockIdx.x / Md, m = blockIdx.x % Md;
    int tid = threadIdx.x;
    if (tid == 0) {
        int acc = 0;
        for (int i = 0; i < bin; i++) acc += binCnt[i];
        boff[0] = acc;
        boff[1] = acc + binCnt[bin];
    }
    for (int i = tid; i < WINDOW; i += 256) cnt[i] = 0;
    __syncthreads();
    int st = boff[0], en = boff[1];
    for (int idx = st + m * 256 + tid; idx < en; idx += Md * 256)
        atomicAdd(&cnt[binnedCol16[idx]], 1u);
    __syncthreads();
    int wb = bin * WINDOW;
    int wlim = (N - wb) < WINDOW ? (N - wb) : WINDOW;
    for (int i = tid; i < wlim; i += 256)
        partialDeg[(size_t)m * N + wb + i] = cnt[i];
}

// dis = 1/sqrt(deg+1); hd = h*dis
__global__ void k_dis_hd(const unsigned int* __restrict__ partialDeg,
                         const double* __restrict__ h,
                         double* __restrict__ dis, double* __restrict__ hd,
                         int N, int Md) {
    int i = blockIdx.x * blockDim.x + threadIdx.x;
    if (i >= N) return;
    unsigned int dsum = 0;
    for (int m = 0; m < Md; m++) dsum += partialDeg[(size_t)m * N + i];
    double d = 1.0 / sqrt((double)dsum + 1.0);
    dis[i] = d;
    hd[i] = h[i] * d;
}

// per-(bin,m) LDS u64 fixed-point accumulate -> coalesced partial store.
__global__ void k_aggb(const int* __restrict__ binnedRow,
                       const unsigned short* __restrict__ binnedCol16,
                       const int* __restrict__ binCnt,
                       const double* __restrict__ hd, const double* __restrict__ dis,
                       unsigned long long* __restrict__ partialAgg, int N, int Ma, int NB) {
    __shared__ unsigned long long acc[WINDOW];   // 15.9 KB
    __shared__ int boff[2];
    int bin = blockIdx.x / Ma, m = blockIdx.x % Ma;
    int tid = threadIdx.x;
    if (tid == 0) {
        int a = 0;
        for (int i = 0; i < bin; i++) a += binCnt[i];
        boff[0] = a;
        boff[1] = a + binCnt[bin];
    }
    for (int i = tid; i < WINDOW; i += 256) acc[i] = 0ULL;
    __syncthreads();
    int st = boff[0], en = boff[1];
    int wb = bin * WINDOW;
    for (int idx = st + m * 256 + tid; idx < en; idx += Ma * 256) {
        int r = binnedRow[idx];
        int c16 = binnedCol16[idx];
        long long q = __double2ll_rn(hd[r] * dis[wb + c16] * FXSCALE);
        atomicAdd(&acc[c16], (unsigned long long)q);
    }
    __syncthreads();
    int wlim = (N - wb) < WINDOW ? (N - wb) : WINDOW;
    for (int i = tid; i < wlim; i += 256)
        partialAgg[(size_t)m * N + wb + i] = acc[i];
}

// score (fp64, rounded to fp32) ; tg = tanh(score) fp32
__global__ void k_score(const unsigned long long* __restrict__ partialAgg,
                        const double* __restrict__ h, const double* __restrict__ dis,
                        const float* __restrict__ bptr,
                        float* __restrict__ score32, float* __restrict__ tg,
                        int N, int Ma) {
    int i = blockIdx.x * blockDim.x + threadIdx.x;
    if (i >= N) return;
    long long acc = 0;
    for (int m = 0; m < Ma; m++) acc += (long long)partialAgg[(size_t)m * N + i];
    double agg = (double)acc / FXSCALE;
    double d = dis[i];
    double sc = (agg + h[i] * (d * d)) + (double)bptr[0];
    score32[i] = (float)sc;
    tg[i] = (float)tanh(sc);
}

// One THREAD per segment — keep numerics byte-identical to passing rounds.
__global__ void k_seg_np(const float* __restrict__ score32, const int* __restrict__ starts,
                         float* __restrict__ p32, int* __restrict__ keepI,
                         const int* __restrict__ alphaPtr,
                         const int* __restrict__ n1, const int* __restrict__ n2,
                         const int* __restrict__ sent, int N, int S) {
    int g = blockIdx.x * blockDim.x + threadIdx.x;
    if (g >= S) return;
    int st = starts[g];
    int en = (g == S - 1) ? N : starts[g + 1];
    if (en <= st) return;

    int ai = alphaPtr[0];
    float alpha = (ai >= 0 && ai < 1000000) ? (float)ai : __int_as_float(ai);

    float m = -3.402823466e38f;
    for (int i = st; i < en; i++) m = fmaxf(m, score32[i]);

    float Z = 0.0f;
    for (int i = st; i < en; i++) {
        float dm = __fsub_rn(score32[i], m);
        float e = (float)exp((double)dm);   // correctly-rounded fp32 exp
        p32[i] = e;
        Z = __fadd_rn(Z, e);
    }

    float sp = 0.0f, sq = 0.0f, pm = -3.402823466e38f;
    for (int i = st; i < en; i++) {
        float p = __fdiv_rn(p32[i], Z);
        p32[i] = p;
        sp = __fadd_rn(sp, p);
        sq = __fadd_rn(sq, __fmul_rn(p, p));
        pm = fmaxf(pm, p);
    }

    float cnt_ = (float)(en - st);
    float mean = __fdiv_rn(sp, cnt_);
    float var = __fsub_rn(__fdiv_rn(sq, cnt_), __fmul_rn(mean, mean));
    float sd = sqrtf(fmaxf(var, 0.0f));
    float cutoff = __fsub_rn(pm, __fmul_rn(alpha, sd));

    for (int i = st; i < en; i++) keepI[i] = (p32[i] >= cutoff) ? 1 : 0;

    keepI[n1[g]] = 1;
    keepI[n2[g]] = 1;
    keepI[sent[g]] = 1;
}

// single-pass decoupled-lookback scan: keepI -> posF/gate/o_keep (atomics only).
__global__ void k_scan(const int* __restrict__ keepI, const float* __restrict__ tg,
                       unsigned long long* __restrict__ stArr,
                       float* __restrict__ posF, float* __restrict__ gate,
                       float* __restrict__ o_keep, int N) {
    int tid = threadIdx.x;
    int b = blockIdx.x;
    long base = (long)b * SCAN_CHUNK + (long)tid * 8;
    int v[8];
    int th = 0;
    #pragma unroll
    for (int k = 0; k < 8; k++) {
        long i = base + k;
        v[k] = (i < N) ? keepI[i] : 0;
        th += v[k];
    }
    __shared__ int sm[256];
    sm[tid] = th; __syncthreads();
    for (int off = 1; off < 256; off <<= 1) {
        int t = (tid >= off) ? sm[tid - off] : 0;
        __syncthreads();
        sm[tid] += t;
        __syncthreads();
    }
    int total = sm[255];
    __shared__ int exclSh;
    if (tid == 0) {
        if (b == 0) {
            atomicExch(&stArr[0], (2ULL << 62) | (unsigned long long)(unsigned)total);
            exclSh = 0;
        } else {
            atomicExch(&stArr[b], (1ULL << 62) | (unsigned long long)(unsigned)total);
            int excl = 0;
            int j = b - 1;
            while (true) {
                unsigned long long s = atomicAdd(&stArr[j], 0ULL);
                unsigned state = (unsigned)(s >> 62);
                if (state == 0) continue;
                excl += (int)(s & 0x3FFFFFFFFFFFFFFFULL);
                if (state == 2u) break;
                j--;
            }
            atomicExch(&stArr[b], (2ULL << 62) | (unsigned long long)(unsigned)(excl + total));
            exclSh = excl;
        }
    }
    __syncthreads();
    int run = exclSh + sm[tid] - th;
    #pragma unroll
    for (int k = 0; k < 8; k++) {
        long i = base + k;
        if (i < N) {
            posF[i] = v[k] ? (float)(run + v[k] - 1) : -1.0f;
            gate[i] = v[k] ? tg[i] : 0.0f;
            o_keep[i] = v[k] ? 1.0f : 0.0f;
            run += v[k];
        }
    }
}

// fused outputs: [0,nxb) x_out float4s; [nxb,nxb+neb4) edges x4; rest nodes
__global__ void k_out(const float4* __restrict__ x4, const float* __restrict__ gate,
                      float* __restrict__ o_x, long total4,
                      const int* __restrict__ erow, const int* __restrict__ ecol,
                      const float* __restrict__ posF,
                      float* __restrict__ o_edge, float* __restrict__ o_ekeep, int E,
                      const int* __restrict__ n1, const int* __restrict__ n2,
                      const int* __restrict__ sent,
                      float* __restrict__ o_n1, float* __restrict__ o_n2,
                      float* __restrict__ o_sent, int S,
                      int nxb, int neb4) {
    int b = blockIdx.x;
    if (b < nxb) {
        long idx = (long)b * blockDim.x + threadIdx.x;
        if (idx >= total4) return;
        int row = (int)(idx >> 5);   // C/4 = 32 float4 per row
        float g = gate[row];
        float4 v = x4[idx];
        vfloat4 r = { v.x * g, v.y * g, v.z * g, v.w * g };
        __builtin_nontemporal_store(r, (vfloat4*)o_x + idx);
    } else if (b < nxb + neb4) {
        long e0 = ((long)(b - nxb) * blockDim.x + threadIdx.x) * 4;
        if (e0 >= E) return;
        if (e0 + 3 < E) {
            int4 r4 = *(const int4*)(erow + e0);
            int4 c4 = *(const int4*)(ecol + e0);
            vfloat4 oer, oec, ok;
            #pragma unroll
            for (int k = 0; k < 4; k++) {
                int r = (&r4.x)[k], c = (&c4.x)[k];
                float pr = posF[r], pc = posF[c];
                bool ek = (pr >= 0.0f) && (pc >= 0.0f);
                oer[k] = ek ? pr : -1.0f;
                oec[k] = ek ? pc : -1.0f;
                ok[k]  = ek ? 1.0f : 0.0f;
            }
            __builtin_nontemporal_store(oer, (vfloat4*)(o_edge + e0));
            __builtin_nontemporal_store(oec, (vfloat4*)(o_edge + (size_t)E + e0));
            __builtin_nontemporal_store(ok,  (vfloat4*)(o_ekeep + e0));
        } else {
            for (long e = e0; e < E; e++) {
                int r = erow[e], c = ecol[e];
                float pr = posF[r], pc = posF[c];
                bool ek = (pr >= 0.0f) && (pc >= 0.0f);
                o_edge[e] = ek ? pr : -1.0f;
                o_edge[(size_t)E + e] = ek ? pc : -1.0f;
                o_ekeep[e] = ek ? 1.0f : 0.0f;
            }
        }
    } else {
        int i = (b - nxb - neb4) * blockDim.x + threadIdx.x;
        if (i >= S) return;
        o_n1[i] = posF[n1[i]];
        o_n2[i] = posF[n2[i]];
        o_sent[i] = posF[sent[i]];
    }
}

extern "C" void kernel_launch(void* const* d_in, const int* in_sizes, int n_in,
                              void* d_out, int out_size, void* d_ws, size_t ws_size,
                              hipStream_t stream) {
    const float* x    = (const float*)d_in[0];
    const int*   eidx = (const int*)d_in[1];
    const int*   n1   = (const int*)d_in[2];
    const int*   n2   = (const int*)d_in[3];
    const int*   sent = (const int*)d_in[4];
    const float* W    = (const float*)d_in[5];
    const float* bp   = (const float*)d_in[6];
    const int*   alphaPtr = (const int*)d_in[7];

    int C = in_sizes[5];                 // W is [C,1]
    int N = in_sizes[0] / C;
    int E = in_sizes[1] / 2;
    int S = in_sizes[2];

    const int* erow = eidx;
    const int* ecol = eidx + E;

    int NB = (N + WINDOW - 1) / WINDOW;  // 101 for N=200000
    const int Md = 8, Ma = 8;

    // workspace layout — zeroed control region first (binCnt + binWr0 + scanSt)
    char* ws = (char*)d_ws;
    size_t off = 0;
    auto alloc = [&](size_t bytes) { void* p = ws + off; off += (bytes + 255) & ~(size_t)255; return p; };
    int*   binCnt = (int*)  alloc(NBMAX * 4);
    int*   binWr0 = (int*)  alloc(NBMAX * 4);
    unsigned long long* scanSt = (unsigned long long*)alloc(256 * 8);
    size_t zeroBytes = (size_t)((char*)(scanSt + 256) - (char*)binCnt);
    int*   binnedRow = (int*)alloc((size_t)E * 4);
    unsigned short* binnedCol16 = (unsigned short*)alloc((size_t)E * 2);
    unsigned int* partialDeg = (unsigned int*)alloc((size_t)Md * N * 4);
    unsigned long long* partialAgg = (unsigned long long*)alloc((size_t)Ma * N * 8);
    double* h     = (double*)alloc((size_t)N * 8);
    double* dis   = (double*)alloc((size_t)N * 8);
    double* hd    = (double*)alloc((size_t)N * 8);
    float* score32 = (float*)alloc((size_t)N * 4);
    float* p32    = (float*)alloc((size_t)N * 4);
    float* tg     = (float*)alloc((size_t)N * 4);
    int*   keepI  = (int*)  alloc((size_t)N * 4);
    float* posF   = (float*)alloc((size_t)N * 4);
    float* gate   = (float*)alloc((size_t)N * 4);

    // output layout (all float32, concatenated)
    float* o_x     = (float*)d_out;
    float* o_edge  = o_x + (size_t)N * C;
    float* o_keep  = o_edge + 2 * (size_t)E;
    float* o_ekeep = o_keep + N;
    float* o_n1    = o_ekeep + E;
    float* o_n2    = o_n1 + S;
    float* o_sent  = o_n2 + S;

    (void)hipMemsetAsync(binCnt, 0, zeroBytes, stream);

    k_hist<<<512, 256, 0, stream>>>(ecol, binCnt, E, NB);
    int nBatches = (int)(((long)E + BINB - 1) / BINB);
    int nhb = (N * 32 + 255) / 256;
    k_bin_h<<<nBatches + nhb, 256, 0, stream>>>(erow, ecol, binCnt, binWr0,
                                                binnedRow, binnedCol16,
                                                x, W, h, E, NB, N, C, nBatches);
    k_degb<<<NB * Md, 256, 0, stream>>>(binnedCol16, binCnt, partialDeg, N, Md, NB);
    k_dis_hd<<<(N + 255) / 256, 256, 0, stream>>>(partialDeg, h, dis, hd, N, Md);
    k_aggb<<<NB * Ma, 256, 0, stream>>>(binnedRow, binnedCol16, binCnt, hd, dis, partialAgg, N, Ma, NB);
    k_score<<<(N + 255) / 256, 256, 0, stream>>>(partialAgg, h, dis, bp, score32, tg, N, Ma);
    k_seg_np<<<(S + 255) / 256, 256, 0, stream>>>(score32, n1, p32, keepI, alphaPtr, n1, n2, sent, N, S);
    int nb = (N + SCAN_CHUNK - 1) / SCAN_CHUNK;
    k_scan<<<nb, 256, 0, stream>>>(keepI, tg, scanSt, posF, gate, o_keep, N);

    long total4 = (long)N * (C / 4);
    int nxb = (int)((total4 + 255) / 256);
    long e4 = (E + 3) / 4;
    int neb4 = (int)((e4 + 255) / 256);
    int nsb = (S + 255) / 256;
    k_out<<<nxb + neb4 + nsb, 256, 0, stream>>>(
        (const float4*)x, gate, o_x, total4,
        erow, ecol, posF, o_edge, o_ekeep, E,
        n1, n2, sent, o_n1, o_n2, o_sent, S, nxb, neb4);
}

// Round 13
// 232.946 us; speedup vs baseline: 1.9088x; 1.0806x over previous
//
#include <hip/hip_runtime.h>
#include <math.h>

#define FXSCALE 4398046511104.0   // 2^42
#define WINDOW 1984               // nodes per col-bin
#define NBMAX 128
#define BINB 2048
#define LDSCAP 12288              // max staged elements per seg-scan block (2*48KB LDS)

typedef float vfloat4 __attribute__((ext_vector_type(4)));

// col-window histogram (512 blocks, LDS counters)
__global__ void k_hist(const int* __restrict__ ecol, int* __restrict__ binCnt,
                       int E, int NB) {
    __shared__ int cnt[NBMAX];
    int tid = threadIdx.x;
    for (int i = tid; i < NBMAX; i += 256) cnt[i] = 0;
    __syncthreads();
    for (long e = (long)blockIdx.x * 256 + tid; e < E; e += 512L * 256)
        atomicAdd(&cnt[ecol[e] / WINDOW], 1);
    __syncthreads();
    for (int i = tid; i < NB; i += 256)
        if (cnt[i] > 0) atomicAdd(&binCnt[i], cnt[i]);
}

// fused: blocks [0,nBatches) partition edges; rest compute h = x@W (fp64).
__global__ void k_bin_h(const int* __restrict__ erow, const int* __restrict__ ecol,
                        const int* __restrict__ binCnt, int* __restrict__ binWr0,
                        int* __restrict__ binnedRow,
                        unsigned short* __restrict__ binnedCol16,
                        const float* __restrict__ x, const float* __restrict__ W,
                        double* __restrict__ h,
                        int E, int NB, int N, int C, int nBatches) {
    int blk = blockIdx.x;
    if (blk >= nBatches) {
        int t = (blk - nBatches) * 256 + threadIdx.x;
        int row = t >> 5;
        int lane = t & 31;
        if (row >= N) return;
        const float4* xr = (const float4*)(x + (size_t)row * C);
        const float4* w4 = (const float4*)W;
        int C4 = C >> 2;
        double acc = 0.0;
        for (int c = lane; c < C4; c += 32) {
            float4 xv = xr[c];
            float4 wv = w4[c];
            acc += (double)xv.x * (double)wv.x + (double)xv.y * (double)wv.y
                 + (double)xv.z * (double)wv.z + (double)xv.w * (double)wv.w;
        }
        #pragma unroll
        for (int o = 16; o > 0; o >>= 1) acc += __shfl_xor(acc, o);
        if (lane == 0) h[row] = acc;
        return;
    }
    __shared__ int cnt[NBMAX];
    __shared__ int bcS[NBMAX];
    __shared__ int lbase[NBMAX];
    __shared__ int gbase[NBMAX];
    __shared__ int lrow[BINB];
    __shared__ unsigned short lcol[BINB];
    __shared__ unsigned char lbin[BINB];
    int tid = threadIdx.x;
    for (int i = tid; i < NBMAX; i += 256) { cnt[i] = 0; bcS[i] = (i < NB) ? binCnt[i] : 0; }
    __syncthreads();
    long b0 = (long)blk * BINB;
    int n = (int)((E - b0) < (long)BINB ? (E - b0) : (long)BINB);
    int bA[8], rkA[8], rwA[8];
    unsigned short clA[8];
    #pragma unroll
    for (int k = 0; k < 8; k++) bA[k] = -1;
    int base_i = tid * 8;
    if (base_i + 8 <= n) {
        long e = b0 + base_i;
        int4 r0 = *(const int4*)(erow + e), r1 = *(const int4*)(erow + e + 4);
        int4 c0 = *(const int4*)(ecol + e), c1 = *(const int4*)(ecol + e + 4);
        int rr[8] = {r0.x, r0.y, r0.z, r0.w, r1.x, r1.y, r1.z, r1.w};
        int cc[8] = {c0.x, c0.y, c0.z, c0.w, c1.x, c1.y, c1.z, c1.w};
        #pragma unroll
        for (int k = 0; k < 8; k++) {
            int c = cc[k];
            int bb = c / WINDOW;
            bA[k] = bb; rwA[k] = rr[k]; clA[k] = (unsigned short)(c - bb * WINDOW);
            rkA[k] = atomicAdd(&cnt[bb], 1);
        }
    } else {
        for (int k = 0; k < 8; k++) {
            int i = base_i + k;
            if (i < n) {
                long e = b0 + i;
                int c = ecol[e];
                int bb = c / WINDOW;
                bA[k] = bb; rwA[k] = erow[e]; clA[k] = (unsigned short)(c - bb * WINDOW);
                rkA[k] = atomicAdd(&cnt[bb], 1);
            }
        }
    }
    __syncthreads();
    if (tid == 0) {
        int acc = 0;
        #pragma unroll 1
        for (int i = 0; i < NB; i++) { lbase[i] = acc; acc += cnt[i]; }
    }
    __syncthreads();
    if (tid < NB && cnt[tid] > 0) {
        int boff = 0;
        for (int i = 0; i < tid; i++) boff += bcS[i];
        gbase[tid] = boff + atomicAdd(&binWr0[tid], cnt[tid]);
    }
    __syncthreads();
    #pragma unroll
    for (int k = 0; k < 8; k++) {
        if (bA[k] >= 0) {
            int l = lbase[bA[k]] + rkA[k];
            lrow[l] = rwA[k];
            lcol[l] = clA[k];
            lbin[l] = (unsigned char)bA[k];
        }
    }
    __syncthreads();
    for (int l = tid; l < n; l += 256) {
        int bb = lbin[l];
        int g = gbase[bb] + (l - lbase[bb]);
        binnedRow[g] = lrow[l];
        binnedCol16[g] = lcol[l];
    }
}

// per-(bin,m) LDS degree histogram -> coalesced partial store
__global__ void k_degb(const unsigned short* __restrict__ binnedCol16,
                       const int* __restrict__ binCnt,
                       unsigned int* __restrict__ partialDeg, int N, int Md, int NB) {
    __shared__ unsigned int cnt[WINDOW];
    __shared__ int bcS[NBMAX];
    __shared__ int boff[2];
    int bin = blockIdx.x / Md, m = blockIdx.x % Md;
    int tid = threadIdx.x;
    for (int i = tid; i < NB; i += 256) bcS[i] = binCnt[i];
    for (int i = tid; i < WINDOW; i += 256) cnt[i] = 0;
    __syncthreads();
    if (tid == 0) {
        int acc = 0;
        for (int i = 0; i < bin; i++) acc += bcS[i];
        boff[0] = acc;
        boff[1] = acc + bcS[bin];
    }
    __syncthreads();
    int st = boff[0], en = boff[1];
    for (int idx = st + m * 256 + tid; idx < en; idx += Md * 256)
        atomicAdd(&cnt[binnedCol16[idx]], 1u);
    __syncthreads();
    int wb = bin * WINDOW;
    int wlim = (N - wb) < WINDOW ? (N - wb) : WINDOW;
    for (int i = tid; i < wlim; i += 256)
        partialDeg[(size_t)m * N + wb + i] = cnt[i];
}

// dis = 1/sqrt(deg+1); hd = h*dis
__global__ void k_dis_hd(const unsigned int* __restrict__ partialDeg,
                         const double* __restrict__ h,
                         double* __restrict__ dis, double* __restrict__ hd,
                         int N, int Md) {
    int i = blockIdx.x * blockDim.x + threadIdx.x;
    if (i >= N) return;
    unsigned int dsum = 0;
    for (int m = 0; m < Md; m++) dsum += partialDeg[(size_t)m * N + i];
    double d = 1.0 / sqrt((double)dsum + 1.0);
    dis[i] = d;
    hd[i] = h[i] * d;
}

// per-(bin,m) LDS u64 fixed-point accumulate -> coalesced partial store.
__global__ void k_aggb(const int* __restrict__ binnedRow,
                       const unsigned short* __restrict__ binnedCol16,
                       const int* __restrict__ binCnt,
                       const double* __restrict__ hd, const double* __restrict__ dis,
                       unsigned long long* __restrict__ partialAgg, int N, int Ma, int NB) {
    __shared__ unsigned long long acc[WINDOW];
    __shared__ int bcS[NBMAX];
    __shared__ int boff[2];
    int bin = blockIdx.x / Ma, m = blockIdx.x % Ma;
    int tid = threadIdx.x;
    for (int i = tid; i < NB; i += 256) bcS[i] = binCnt[i];
    for (int i = tid; i < WINDOW; i += 256) acc[i] = 0ULL;
    __syncthreads();
    if (tid == 0) {
        int a = 0;
        for (int i = 0; i < bin; i++) a += bcS[i];
        boff[0] = a;
        boff[1] = a + bcS[bin];
    }
    __syncthreads();
    int st = boff[0], en = boff[1];
    int wb = bin * WINDOW;
    for (int idx = st + m * 256 + tid; idx < en; idx += Ma * 256) {
        int r = binnedRow[idx];
        int c16 = binnedCol16[idx];
        long long q = __double2ll_rn(hd[r] * dis[wb + c16] * FXSCALE);
        atomicAdd(&acc[c16], (unsigned long long)q);
    }
    __syncthreads();
    int wlim = (N - wb) < WINDOW ? (N - wb) : WINDOW;
    for (int i = tid; i < wlim; i += 256)
        partialAgg[(size_t)m * N + wb + i] = acc[i];
}

// score (fp64, rounded to fp32) ; tg = tanh(score) fp32
__global__ void k_score(const unsigned long long* __restrict__ partialAgg,
                        const double* __restrict__ h, const double* __restrict__ dis,
                        const float* __restrict__ bptr,
                        float* __restrict__ score32, float* __restrict__ tg,
                        int N, int Ma) {
    int i = blockIdx.x * blockDim.x + threadIdx.x;
    if (i >= N) return;
    long long acc = 0;
    for (int m = 0; m < Ma; m++) acc += (long long)partialAgg[(size_t)m * N + i];
    double agg = (double)acc / FXSCALE;
    double d = dis[i];
    double sc = (agg + h[i] * (d * d)) + (double)bptr[0];
    score32[i] = (float)sc;
    tg[i] = (float)tanh(sc);
}

// FUSED segment softmax/cutoff/keep + decoupled-lookback compaction.
// Block = 256 consecutive segments (contiguous node range). Scores staged in
// LDS; per-segment fp32 sequence is op-for-op identical to prior passing
// rounds (same values read from LDS). Positions assigned in LDS, block totals
// stitched via atomics-only lookback, coalesced writeback.
__global__ void k_seg_scan(const float* __restrict__ score32, const float* __restrict__ tg,
                           const int* __restrict__ starts, const int* __restrict__ alphaPtr,
                           const int* __restrict__ n1, const int* __restrict__ n2,
                           const int* __restrict__ sent,
                           unsigned long long* __restrict__ stArr,
                           float* __restrict__ p32, int* __restrict__ keepG,
                           float* __restrict__ posF, float* __restrict__ gate,
                           float* __restrict__ o_keep, int N, int S) {
    __shared__ float scoreS[LDSCAP];   // staged scores, later reused for keep flags
    __shared__ float pS[LDSCAP];       // e -> p -> posF values
    __shared__ int smc[256];
    __shared__ int exclSh;
    int tid = threadIdx.x;
    int b = blockIdx.x;
    int g0 = b * 256;
    int segs = S - g0; if (segs > 256) segs = 256;
    int st0 = starts[g0];
    int en0 = (g0 + 256 >= S) ? N : starts[g0 + 256];
    int len = en0 - st0;
    bool useLds = (len <= LDSCAP);

    int ai = alphaPtr[0];
    float alpha = (ai >= 0 && ai < 1000000) ? (float)ai : __int_as_float(ai);

    int myKept = 0;
    int myStL = 0, myEnL = 0;
    bool active = false;

    if (useLds) {
        for (int i = tid; i < len; i += 256) scoreS[i] = score32[st0 + i];
        __syncthreads();
        int g = g0 + tid;
        if (tid < segs) {
            int st = starts[g] - st0;
            int en = ((g == S - 1) ? N : starts[g + 1]) - st0;
            if (en > st) {
                active = true; myStL = st; myEnL = en;
                float m = -3.402823466e38f;
                for (int i = st; i < en; i++) m = fmaxf(m, scoreS[i]);
                float Z = 0.0f;
                for (int i = st; i < en; i++) {
                    float dm = __fsub_rn(scoreS[i], m);
                    float e = (float)exp((double)dm);
                    pS[i] = e;
                    Z = __fadd_rn(Z, e);
                }
                float sp = 0.0f, sq = 0.0f, pm = -3.402823466e38f;
                for (int i = st; i < en; i++) {
                    float p = __fdiv_rn(pS[i], Z);
                    pS[i] = p;
                    sp = __fadd_rn(sp, p);
                    sq = __fadd_rn(sq, __fmul_rn(p, p));
                    pm = fmaxf(pm, p);
                }
                float cnt_ = (float)(en - st);
                float mean = __fdiv_rn(sp, cnt_);
                float var = __fsub_rn(__fdiv_rn(sq, cnt_), __fmul_rn(mean, mean));
                float sd = sqrtf(fmaxf(var, 0.0f));
                float cutoff = __fsub_rn(pm, __fmul_rn(alpha, sd));
                for (int i = st; i < en; i++)
                    scoreS[i] = (pS[i] >= cutoff) ? 1.0f : 0.0f;
                scoreS[n1[g] - st0] = 1.0f;     // special nodes lie inside own segment
                scoreS[n2[g] - st0] = 1.0f;
                scoreS[sent[g] - st0] = 1.0f;
                int c = 0;
                for (int i = st; i < en; i++) c += (scoreS[i] != 0.0f) ? 1 : 0;
                myKept = c;
            }
        }
    } else {
        // global fallback (not taken for this dataset) — same numerics via p32/keepG
        int g = g0 + tid;
        if (tid < segs) {
            int st = starts[g];
            int en = (g == S - 1) ? N : starts[g + 1];
            if (en > st) {
                active = true; myStL = st - st0; myEnL = en - st0;
                float m = -3.402823466e38f;
                for (int i = st; i < en; i++) m = fmaxf(m, score32[i]);
                float Z = 0.0f;
                for (int i = st; i < en; i++) {
                    float dm = __fsub_rn(score32[i], m);
                    float e = (float)exp((double)dm);
                    p32[i] = e;
                    Z = __fadd_rn(Z, e);
                }
                float sp = 0.0f, sq = 0.0f, pm = -3.402823466e38f;
                for (int i = st; i < en; i++) {
                    float p = __fdiv_rn(p32[i], Z);
                    p32[i] = p;
                    sp = __fadd_rn(sp, p);
                    sq = __fadd_rn(sq, __fmul_rn(p, p));
                    pm = fmaxf(pm, p);
                }
                float cnt_ = (float)(en - st);
                float mean = __fdiv_rn(sp, cnt_);
                float var = __fsub_rn(__fdiv_rn(sq, cnt_), __fmul_rn(mean, mean));
                float sd = sqrtf(fmaxf(var, 0.0f));
                float cutoff = __fsub_rn(pm, __fmul_rn(alpha, sd));
                for (int i = st; i < en; i++) keepG[i] = (p32[i] >= cutoff) ? 1 : 0;
                keepG[n1[g]] = 1; keepG[n2[g]] = 1; keepG[sent[g]] = 1;
                int c = 0;
                for (int i = st; i < en; i++) c += keepG[i];
                myKept = c;
            }
        }
    }
    smc[tid] = myKept;
    __syncthreads();
    for (int off2 = 1; off2 < 256; off2 <<= 1) {
        int t = (tid >= off2) ? smc[tid - off2] : 0;
        __syncthreads();
        smc[tid] += t;
        __syncthreads();
    }
    int total = smc[255];
    if (tid == 0) {
        if (b == 0) {
            atomicExch(&stArr[0], (2ULL << 62) | (unsigned long long)(unsigned)total);
            exclSh = 0;
        } else {
            atomicExch(&stArr[b], (1ULL << 62) | (unsigned long long)(unsigned)total);
            int excl = 0;
            int j = b - 1;
            while (true) {
                unsigned long long s = atomicAdd(&stArr[j], 0ULL);
                unsigned state = (unsigned)(s >> 62);
                if (state == 0) continue;
                excl += (int)(s & 0x3FFFFFFFFFFFFFFFULL);
                if (state == 2u) break;
                j--;
            }
            atomicExch(&stArr[b], (2ULL << 62) | (unsigned long long)(unsigned)(excl + total));
            exclSh = excl;
        }
    }
    __syncthreads();
    if (active) {
        int run = exclSh + smc[tid] - myKept;
        if (useLds) {
            for (int i = myStL; i < myEnL; i++) {
                if (scoreS[i] != 0.0f) { pS[i] = (float)run; run++; }
                else pS[i] = -1.0f;
            }
        } else {
            for (int i = myStL; i < myEnL; i++) {
                if (keepG[st0 + i]) { p32[st0 + i] = (float)run; run++; }
                else p32[st0 + i] = -1.0f;
            }
        }
    }
    __syncthreads();
    for (int i = tid; i < len; i += 256) {
        float pv = useLds ? pS[i] : p32[st0 + i];
        bool v = (pv >= 0.0f);
        posF[st0 + i] = pv;
        o_keep[st0 + i] = v ? 1.0f : 0.0f;
        gate[st0 + i] = v ? tg[st0 + i] : 0.0f;
    }
}

// fused outputs: [0,nxb) x_out float4s; [nxb,nxb+neb4) edges x4; rest nodes
__global__ void k_out(const float4* __restrict__ x4, const float* __restrict__ gate,
                      float* __restrict__ o_x, long total4,
                      const int* __restrict__ erow, const int* __restrict__ ecol,
                      const float* __restrict__ posF,
                      float* __restrict__ o_edge, float* __restrict__ o_ekeep, int E,
                      const int* __restrict__ n1, const int* __restrict__ n2,
                      const int* __restrict__ sent,
                      float* __restrict__ o_n1, float* __restrict__ o_n2,
                      float* __restrict__ o_sent, int S,
                      int nxb, int neb4) {
    int b = blockIdx.x;
    if (b < nxb) {
        long idx = (long)b * blockDim.x + threadIdx.x;
        if (idx >= total4) return;
        int row = (int)(idx >> 5);   // C/4 = 32 float4 per row
        float g = gate[row];
        float4 v = x4[idx];
        vfloat4 r = { v.x * g, v.y * g, v.z * g, v.w * g };
        __builtin_nontemporal_store(r, (vfloat4*)o_x + idx);
    } else if (b < nxb + neb4) {
        long e0 = ((long)(b - nxb) * blockDim.x + threadIdx.x) * 4;
        if (e0 >= E) return;
        if (e0 + 3 < E) {
            int4 r4 = *(const int4*)(erow + e0);
            int4 c4 = *(const int4*)(ecol + e0);
            vfloat4 oer, oec, ok;
            #pragma unroll
            for (int k = 0; k < 4; k++) {
                int r = (&r4.x)[k], c = (&c4.x)[k];
                float pr = posF[r], pc = posF[c];
                bool ek = (pr >= 0.0f) && (pc >= 0.0f);
                oer[k] = ek ? pr : -1.0f;
                oec[k] = ek ? pc : -1.0f;
                ok[k]  = ek ? 1.0f : 0.0f;
            }
            __builtin_nontemporal_store(oer, (vfloat4*)(o_edge + e0));
            __builtin_nontemporal_store(oec, (vfloat4*)(o_edge + (size_t)E + e0));
            __builtin_nontemporal_store(ok,  (vfloat4*)(o_ekeep + e0));
        } else {
            for (long e = e0; e < E; e++) {
                int r = erow[e], c = ecol[e];
                float pr = posF[r], pc = posF[c];
                bool ek = (pr >= 0.0f) && (pc >= 0.0f);
                o_edge[e] = ek ? pr : -1.0f;
                o_edge[(size_t)E + e] = ek ? pc : -1.0f;
                o_ekeep[e] = ek ? 1.0f : 0.0f;
            }
        }
    } else {
        int i = (b - nxb - neb4) * blockDim.x + threadIdx.x;
        if (i >= S) return;
        o_n1[i] = posF[n1[i]];
        o_n2[i] = posF[n2[i]];
        o_sent[i] = posF[sent[i]];
    }
}

extern "C" void kernel_launch(void* const* d_in, const int* in_sizes, int n_in,
                              void* d_out, int out_size, void* d_ws, size_t ws_size,
                              hipStream_t stream) {
    const float* x    = (const float*)d_in[0];
    const int*   eidx = (const int*)d_in[1];
    const int*   n1   = (const int*)d_in[2];
    const int*   n2   = (const int*)d_in[3];
    const int*   sent = (const int*)d_in[4];
    const float* W    = (const float*)d_in[5];
    const float* bp   = (const float*)d_in[6];
    const int*   alphaPtr = (const int*)d_in[7];

    int C = in_sizes[5];                 // W is [C,1]
    int N = in_sizes[0] / C;
    int E = in_sizes[1] / 2;
    int S = in_sizes[2];

    const int* erow = eidx;
    const int* ecol = eidx + E;

    int NB = (N + WINDOW - 1) / WINDOW;  // 101 for N=200000
    const int Md = 8, Ma = 8;
    int nsegb = (S + 255) / 256;         // seg-scan blocks
    int stN = nsegb > 256 ? nsegb : 256;

    // workspace layout — zeroed control region first (binCnt + binWr0 + scanSt)
    char* ws = (char*)d_ws;
    size_t off = 0;
    auto alloc = [&](size_t bytes) { void* p = ws + off; off += (bytes + 255) & ~(size_t)255; return p; };
    int*   binCnt = (int*)  alloc(NBMAX * 4);
    int*   binWr0 = (int*)  alloc(NBMAX * 4);
    unsigned long long* scanSt = (unsigned long long*)alloc((size_t)stN * 8);
    size_t zeroBytes = (size_t)((char*)(scanSt + stN) - (char*)binCnt);
    int*   binnedRow = (int*)alloc((size_t)E * 4);
    unsigned short* binnedCol16 = (unsigned short*)alloc((size_t)E * 2);
    unsigned int* partialDeg = (unsigned int*)alloc((size_t)Md * N * 4);
    unsigned long long* partialAgg = (unsigned long long*)alloc((size_t)Ma * N * 8);
    double* h     = (double*)alloc((size_t)N * 8);
    double* dis   = (double*)alloc((size_t)N * 8);
    double* hd    = (double*)alloc((size_t)N * 8);
    float* score32 = (float*)alloc((size_t)N * 4);
    float* p32    = (float*)alloc((size_t)N * 4);
    float* tg     = (float*)alloc((size_t)N * 4);
    int*   keepG  = (int*)  alloc((size_t)N * 4);
    float* posF   = (float*)alloc((size_t)N * 4);
    float* gate   = (float*)alloc((size_t)N * 4);

    // output layout (all float32, concatenated)
    float* o_x     = (float*)d_out;
    float* o_edge  = o_x + (size_t)N * C;
    float* o_keep  = o_edge + 2 * (size_t)E;
    float* o_ekeep = o_keep + N;
    float* o_n1    = o_ekeep + E;
    float* o_n2    = o_n1 + S;
    float* o_sent  = o_n2 + S;

    (void)hipMemsetAsync(binCnt, 0, zeroBytes, stream);

    k_hist<<<512, 256, 0, stream>>>(ecol, binCnt, E, NB);
    int nBatches = (int)(((long)E + BINB - 1) / BINB);
    int nhb = (N * 32 + 255) / 256;
    k_bin_h<<<nBatches + nhb, 256, 0, stream>>>(erow, ecol, binCnt, binWr0,
                                                binnedRow, binnedCol16,
                                                x, W, h, E, NB, N, C, nBatches);
    k_degb<<<NB * Md, 256, 0, stream>>>(binnedCol16, binCnt, partialDeg, N, Md, NB);
    k_dis_hd<<<(N + 255) / 256, 256, 0, stream>>>(partialDeg, h, dis, hd, N, Md);
    k_aggb<<<NB * Ma, 256, 0, stream>>>(binnedRow, binnedCol16, binCnt, hd, dis, partialAgg, N, Ma, NB);
    k_score<<<(N + 255) / 256, 256, 0, stream>>>(partialAgg, h, dis, bp, score32, tg, N, Ma);
    k_seg_scan<<<nsegb, 256, 0, stream>>>(score32, tg, n1, alphaPtr, n1, n2, sent,
                                          scanSt, p32, keepG, posF, gate, o_keep, N, S);

    long total4 = (long)N * (C / 4);
    int nxb = (int)((total4 + 255) / 256);
    long e4 = (E + 3) / 4;
    int neb4 = (int)((e4 + 255) / 256);
    int nsb = (S + 255) / 256;
    k_out<<<nxb + neb4 + nsb, 256, 0, stream>>>(
        (const float4*)x, gate, o_x, total4,
        erow, ecol, posF, o_edge, o_ekeep, E,
        n1, n2, sent, o_n1, o_n2, o_sent, S, nxb, neb4);
}